// Round 12
// baseline (401.905 us; speedup 1.0000x reference)
//
#include <hip/hip_runtime.h>
#include <float.h>
#include <stdint.h>

// Problem constants
#define BB   128      // bs*t
#define CCH  256      // z channels
#define EMB_ 256      // embedding dim
#define HW   256      // h*w
#define NPIX 32768    // BB*HW
#define VOC  4096

typedef _Float16 f16x8 __attribute__((ext_vector_type(8)));
typedef float    f32x4 __attribute__((ext_vector_type(4)));

// async global->LDS, 16B per lane, dest = wave-uniform base + lane*16
__device__ __forceinline__ void async16(void* lds, const void* g) {
    __builtin_amdgcn_global_load_lds((const __attribute__((address_space(1))) uint32_t*)g,
                                     (__attribute__((address_space(3))) uint32_t*)lds,
                                     16, 0, 0);
}

// ===================== K_PREP: small preprocessing (544 blocks) ============
__global__ __launch_bounds__(256) void k_prep(const float* __restrict__ cb,
                                              const float* __restrict__ post_w,
                                              const float* __restrict__ post_b,
                                              const float* __restrict__ pre_w,
                                              float* __restrict__ postcode,
                                              _Float16* __restrict__ B3,
                                              float* __restrict__ csq,
                                              _Float16* __restrict__ W3) {
    __shared__ float smem[4352];              // 17 KB union
    const int bid = blockIdx.x;
    const int tid = threadIdx.x;

    if (bid < 256) {
        // ---------------- postcode ----------------
        float (*cbs)[EMB_] = (float(*)[EMB_])smem;          // [16][256]
        int v0 = bid * 16;
        int c  = tid;
#pragma unroll
        for (int r = 0; r < 16; ++r)
            cbs[r][c] = cb[(v0 + r) * EMB_ + c];
        __syncthreads();
        float acc[16];
        float bias = post_b[c];
#pragma unroll
        for (int r = 0; r < 16; ++r) acc[r] = bias;
        const float4* w4p = (const float4*)(post_w + c * EMB_);
        for (int e4 = 0; e4 < 64; ++e4) {
            float4 w4 = w4p[e4];
#pragma unroll
            for (int r = 0; r < 16; ++r) {
                float4 c4 = *(const float4*)&cbs[r][e4 * 4];
                acc[r] = fmaf(w4.x, c4.x, fmaf(w4.y, c4.y,
                         fmaf(w4.z, c4.z, fmaf(w4.w, c4.w, acc[r]))));
            }
        }
#pragma unroll
        for (int r = 0; r < 16; ++r)
            postcode[(v0 + r) * CCH + c] = acc[r];
    } else if (bid < 512) {
        // ---------------- prep_c ----------------
        float (*cs)[17] = (float(*)[17])smem;               // [256][17]
        int vg = bid - 256;
        int vr = tid >> 4, e0 = (tid & 15) << 4;
        const float* cp = cb + (vg * 16 + vr) * EMB_ + e0;
#pragma unroll
        for (int j = 0; j < 16; ++j)
            cs[e0 + j][vr] = cp[j];
        __syncthreads();
#pragma unroll
        for (int it = 0; it < 4; ++it) {
            int c = it * 256 + tid;
            int kc8 = c >> 4, row = c & 15;
            int lo = kc8 >> 5;
            int kh = kc8 & 31;
            f16x8 outv;
#pragma unroll
            for (int j = 0; j < 8; ++j) {
                float v = cs[kh * 8 + j][row] * 65536.0f;   // exact 2^16 scale
                _Float16 h = (_Float16)v;
                if (lo) h = (_Float16)(v - (float)h);
                outv[j] = h;
            }
            *(f16x8*)(B3 + ((vg * 64 + kc8) * 128 + row * 8)) = outv;
        }
    } else if (bid < 528) {
        // ---------------- csq ----------------
        int v = (bid - 512) * 256 + tid;
        const float4* row = (const float4*)(cb + v * EMB_);
        float s = 0.f;
#pragma unroll 8
        for (int q = 0; q < 64; ++q) {
            float4 a = row[q];
            s = fmaf(a.x, a.x, fmaf(a.y, a.y, fmaf(a.z, a.z, fmaf(a.w, a.w, s))));
        }
        csq[v] = s;
    } else {
        // ---------------- prep_w: scaled split of pre_w ----------------
        int eg = bid - 528;                   // 0..15
#pragma unroll
        for (int i = 0; i < 4; ++i) {
            int flat = i * 256 + tid;         // 0..1023 = [u64][row16]
            int u = flat >> 4, row = flat & 15;
            int part = u >> 5, c8 = u & 31;
            const float* wp = pre_w + (eg * 16 + row) * CCH + c8 * 8;
            f16x8 outv;
#pragma unroll
            for (int j = 0; j < 8; ++j) {
                float v = wp[j] * 16.0f;                    // exact 2^4 scale
                _Float16 h = (_Float16)v;
                if (part) h = (_Float16)((v - (float)h) * 4096.0f); // exact*2^12, RN
                outv[j] = h;
            }
            *(f16x8*)(W3 + ((eg * 64 + u) * 128 + row * 8)) = outv;
        }
    }
}

// ============ K1: z-GEMM on MFMA, v3: 64-px blocks, W->reg, no aliasing ====
// Math/chain order identical to the PASSING v1: per cc, accA += wh.xh;
// accB += wh.xl; accB += wl.xh. z = fmaf(accB,2^-12,accA)*2^-4 + pre_b;
// pack v=z*256, hi=fl16(v), lo=fl16(v-hi). -> z_out/A3 bit-identical.
// vs R10's failed v2: pre_b now in REGISTERS (no pbs LDS region at all) and
// the epilogue zw region is DEDICATED (smem+16384..36864), fully disjoint
// from the X buffers (0..16384). 36KB LDS + <=128 VGPR -> 2 blocks/CU.
__global__ __launch_bounds__(512, 4) void k_zgemm(const float* __restrict__ x,
                                                  const _Float16* __restrict__ W3,
                                                  const float* __restrict__ pre_b,
                                                  float* __restrict__ zout,
                                                  _Float16* __restrict__ A3) {
    __shared__ __align__(16) char smem[36864];
    // Xh[2] @0 (4KB each: 0..8192), Xl[2] @8192..16384, zw @16384..36864.

    const int tid = threadIdx.x;
    const int l   = tid & 63;
    const int w   = tid >> 6;
    const int l15 = l & 15, l4 = l >> 4;
    const int wr  = w >> 2, wc = w & 3;       // 2 n-rows x 4 e-cols of waves
    const int bQ  = blockIdx.x;               // grid 512
    const int b   = bQ >> 2, hw0 = (bQ & 3) * 64;

    // X staging: 256 threads, slot (ng,u,row); 8 channels (j) each.
    const int xng = tid >> 6, xu = (tid >> 4) & 3, xrow = tid & 15;
    const float* xbase = x + (size_t)b * (CCH * HW) + hw0 + xng * 16 + xrow;

#define STAGE_X(CC, BUF) {                                                   \
    if (tid < 256) {                                                         \
        const float* xp_ = xbase + ((CC) * 32 + xu * 8) * HW;                \
        f16x8 hv, lv;                                                        \
        _Pragma("unroll")                                                    \
        for (int j = 0; j < 8; ++j) {                                        \
            float xv = 2.0f * xp_[j * HW] - 1.0f;        /* exact */         \
            _Float16 h = (_Float16)xv;                                       \
            lv[j] = (_Float16)((xv - (float)h) * 4096.0f); /* exact 2^12 */  \
            hv[j] = h;                                                       \
        }                                                                    \
        int slot = ((xng * 4 + xu) * 16 + xrow) * 8;                         \
        *(f16x8*)((_Float16*)(smem + (BUF) * 4096) + slot) = hv;             \
        *(f16x8*)((_Float16*)(smem + 8192 + (BUF) * 4096) + slot) = lv;      \
    } }

    // pre_b -> registers (static indexing; no LDS)
    float4 pb4[4];
#pragma unroll
    for (int m = 0; m < 4; ++m)
        pb4[m] = *(const float4*)&pre_b[wc * 64 + m * 16 + l4 * 4];

    STAGE_X(0, 0)
    __syncthreads();

    // W fragment bases (loop-invariant); per cc advance by 4 kc8-units.
    const _Float16* wbase[4];
#pragma unroll
    for (int m = 0; m < 4; ++m)
        wbase[m] = W3 + ((size_t)(wc * 4 + m) * 64 + l4) * 128 + l15 * 8;

    f32x4 accA[4][2], accB[4][2];
    const f32x4 zero4 = {0.f, 0.f, 0.f, 0.f};
#pragma unroll
    for (int m = 0; m < 4; ++m)
#pragma unroll
        for (int s = 0; s < 2; ++s) { accA[m][s] = zero4; accB[m][s] = zero4; }

    int buf = 0;
    for (int cc = 0; cc < 8; ++cc) {
        if (cc < 7) STAGE_X(cc + 1, buf ^ 1)
        // W fragments: global (L2-hot, 256KB array shared by all blocks) -> regs
        f16x8 whf[4], wlf[4];
#pragma unroll
        for (int m = 0; m < 4; ++m) {
            whf[m] = *(const f16x8*)(wbase[m] + (size_t)cc * 512);
            wlf[m] = *(const f16x8*)(wbase[m] + (size_t)cc * 512 + 4096);
        }
        // X fragments from LDS
        f16x8 xhf[2], xlf[2];
#pragma unroll
        for (int s = 0; s < 2; ++s) {
            int xoff = (((wr * 2 + s) * 4 + l4) * 16 + l15) * 8;
            xhf[s] = *(const f16x8*)((_Float16*)(smem + buf * 4096) + xoff);
            xlf[s] = *(const f16x8*)((_Float16*)(smem + 8192 + buf * 4096) + xoff);
        }
#pragma unroll
        for (int m = 0; m < 4; ++m)
#pragma unroll
            for (int s = 0; s < 2; ++s)
                accA[m][s] = __builtin_amdgcn_mfma_f32_16x16x32_f16(whf[m], xhf[s], accA[m][s], 0, 0, 0);
#pragma unroll
        for (int m = 0; m < 4; ++m)
#pragma unroll
            for (int s = 0; s < 2; ++s)
                accB[m][s] = __builtin_amdgcn_mfma_f32_16x16x32_f16(whf[m], xlf[s], accB[m][s], 0, 0, 0);
#pragma unroll
        for (int m = 0; m < 4; ++m)
#pragma unroll
            for (int s = 0; s < 2; ++s)
                accB[m][s] = __builtin_amdgcn_mfma_f32_16x16x32_f16(wlf[m], xhf[s], accB[m][s], 0, 0, 0);
        __syncthreads();
        buf ^= 1;
    }

    // ---- epilogue: z = combine + bias; store z_out; pack A3 (per-wave LDS)
    // zw: DEDICATED region, per-wave disjoint: [32 n][20 floats] each.
    float* zw = (float*)(smem + 16384 + w * 2560);
    const size_t zbase = (size_t)b * (EMB_ * HW) + hw0;
#pragma unroll
    for (int m = 0; m < 4; ++m) {
        asm volatile("s_waitcnt lgkmcnt(0)" ::: "memory");   // prev pack reads done
        __builtin_amdgcn_sched_barrier(0);
        f32x4 zv[2];
#pragma unroll
        for (int s = 0; s < 2; ++s) {
#pragma unroll
            for (int r = 0; r < 4; ++r) {
                float g = fmaf(accB[m][s][r], 0x1p-12f, accA[m][s][r]) * 0x1p-4f;
                zv[s][r] = g + pb4[m][r];
            }
            *(f32x4*)(zw + (s * 16 + l15) * 20 + l4 * 4) = zv[s];
#pragma unroll
            for (int r = 0; r < 4; ++r)
                zout[zbase + (size_t)(wc * 64 + m * 16 + l4 * 4 + r) * HW
                     + wr * 32 + s * 16 + l15] = zv[s][r];
        }
        asm volatile("s_waitcnt lgkmcnt(0)" ::: "memory");   // zw writes visible
        __builtin_amdgcn_sched_barrier(0);
#pragma unroll
        for (int o = 0; o < 2; ++o) {
            int flat = o * 64 + l;            // 0..127
            int part = flat >> 6, rest = flat & 63;
            int pg2 = rest >> 5, uq = (rest >> 4) & 1, row = rest & 15;
            int nloc = pg2 * 16 + row;
            float4 va = *(const float4*)(zw + nloc * 20 + uq * 8);
            float4 vb = *(const float4*)(zw + nloc * 20 + uq * 8 + 4);
            float vs[8] = {va.x, va.y, va.z, va.w, vb.x, vb.y, vb.z, vb.w};
            f16x8 outv;
#pragma unroll
            for (int j = 0; j < 8; ++j) {
                float v = vs[j] * 256.0f;                    // exact 2^8 scale
                _Float16 h = (_Float16)v;
                if (part) h = (_Float16)(v - (float)h);      // exact residual, RN
                outv[j] = h;
            }
            int pixg = b * 16 + (bQ & 3) * 4 + wr * 2 + pg2;
            *(f16x8*)(A3 + ((size_t)pixg * 64
                            + part * 32 + wc * 8 + m * 2 + uq) * 128 + row * 8) = outv;
        }
    }
#undef STAGE_X
}

// --------- K2 staging: BK=32 chunk = 4 contiguous kc8 units at offset kA/kB.
__device__ __forceinline__ void issueA(const _Float16* __restrict__ A3, int bM,
                                       int w, int l, _Float16* dst, int kA) {
#pragma unroll
    for (int i = 0; i < 2; ++i) {
        int pg = 2 * w + i;                           // pixel-group 0..15
        const _Float16* g = A3 + ((bM * 16 + pg) * 64 + kA) * 128 + l * 8;
        async16(dst + pg * 512, g);                   // linear both sides
    }
}

__device__ __forceinline__ void issueB(const _Float16* __restrict__ B3, int vgbase,
                                       int w, int l, _Float16* dst, int kB) {
#pragma unroll
    for (int i = 0; i < 2; ++i) {
        int vg = 2 * w + i;                           // code-group 0..15
        const _Float16* g = B3 + ((vgbase + vg) * 64 + kB) * 128 + l * 8;
        async16(dst + vg * 512, g);
    }
}

// --------------------------------- K2: MFMA distance GEMM + fused argmin
// R4/R5 proven config (234-240 us, no spill): 3 buffers, runtime cur,
// depth-2 prefetch, vmcnt(4), 2 phases per BK=32 chunk. UNCHANGED.
__global__ __launch_bounds__(512) void k_dist(const float* __restrict__ zout,
                                              const _Float16* __restrict__ A3,
                                              const _Float16* __restrict__ B3,
                                              const float* __restrict__ csq,
                                              float* __restrict__ bestw,
                                              int* __restrict__ bidxw) {
    __shared__ __align__(16) _Float16 Ab[3][8192];    // 48 KB (16 KB/chunk)
    __shared__ __align__(16) _Float16 Bb[3][8192];    // 48 KB
    __shared__ float csq_s[2048];                     // 8 KB (this half only)
    __shared__ float zsq_s[256];
    __shared__ float red_b[8][128];
    __shared__ int   red_i[8][128];

    const int tid = threadIdx.x;
    const int l   = tid & 63;
    const int w   = tid >> 6;
    const int l15 = l & 15, l4 = l >> 4;
    const int wr  = w >> 2, wc = w & 3;               // 2M x 4N wave grid
    const int bM  = blockIdx.x & 127;                 // M-tile (256 pixels)
    const int nh  = blockIdx.x >> 7;                  // code half 0/1
    const int vgb = nh * 128;                         // B3 group base

    // prologue: stage chunks 0 and 1
    issueA(A3, bM, w, l, Ab[0], 0);
    issueB(B3, vgb, w, l, Bb[0], 0);
    issueA(A3, bM, w, l, Ab[1], 4);
    issueB(B3, vgb, w, l, Bb[1], 4);

    // csq half -> LDS
#pragma unroll
    for (int j = 0; j < 4; ++j) csq_s[j * 512 + tid] = csq[nh * 2048 + j * 512 + tid];

    // zsq: serial fmaf chain over e (identical rounding to passing kernel)
    if (tid < 256) {
        const float* zp = zout + bM * (EMB_ * HW) + tid;
        float s = 0.f;
        for (int k = 0; k < 256; ++k) { float zv = zp[k * HW]; s = fmaf(zv, zv, s); }
        zsq_s[tid] = s;
    }
    __syncthreads();   // one-time full drain: chunks 0,1 + csq_s + zsq_s ready

    float best[32]; int bidx[32];
#pragma unroll
    for (int i = 0; i < 32; ++i) { best[i] = FLT_MAX; bidx[i] = 0; }

    const f32x4 zero4 = {0.f, 0.f, 0.f, 0.f};
    int cur = 0;
    for (int vt = 0; vt < 8; ++vt) {
        f32x4 acc[8][4];
#pragma unroll
        for (int s = 0; s < 8; ++s)
#pragma unroll
            for (int m = 0; m < 4; ++m) acc[s][m] = zero4;

        for (int kc = 0; kc < 24; ++kc) {
            const int n = vt * 24 + kc;               // global chunk 0..191
            int kc2 = kc + 2, vt2 = vt;
            if (kc2 >= 24) { kc2 -= 24; ++vt2; }
            const int nxt = (cur + 2 >= 3) ? cur - 1 : cur + 2;
            const bool pf = (vt2 < 8);
            const int kA2 = ((kc2 >= 16) ? 32 : 0) + (kc2 & 7) * 4;
            const int kB2 = ((kc2 >= 8 && kc2 < 16) ? 32 : 0) + (kc2 & 7) * 4;

            // ---------------- phase 0: s-half 0 ----------------
            f16x8 af0[4], bf[4];
#pragma unroll
            for (int s = 0; s < 4; ++s)
                af0[s] = *(const f16x8*)&Ab[cur][(wr * 8 + s) * 512 + l4 * 128 + l15 * 8];
#pragma unroll
            for (int m = 0; m < 4; ++m)
                bf[m] = *(const f16x8*)&Bb[cur][(wc * 4 + m) * 512 + l4 * 128 + l15 * 8];
            if (pf) issueA(A3, bM, w, l, Ab[nxt], kA2);
            __builtin_amdgcn_s_barrier();
            asm volatile("s_waitcnt lgkmcnt(0)" ::: "memory");
            __builtin_amdgcn_sched_barrier(0);
            __builtin_amdgcn_s_setprio(1);
#pragma unroll
            for (int s = 0; s < 4; ++s)
#pragma unroll
                for (int m = 0; m < 4; ++m)
                    acc[s][m] = __builtin_amdgcn_mfma_f32_16x16x32_f16(af0[s], bf[m], acc[s][m], 0, 0, 0);
            __builtin_amdgcn_s_setprio(0);
            __builtin_amdgcn_s_barrier();

            // ---------------- phase 1: s-half 1 ----------------
            f16x8 af1[4];
#pragma unroll
            for (int s = 0; s < 4; ++s)
                af1[s] = *(const f16x8*)&Ab[cur][(wr * 8 + 4 + s) * 512 + l4 * 128 + l15 * 8];
            if (pf) issueB(B3, vgb + vt2 * 16, w, l, Bb[nxt], kB2);
            __builtin_amdgcn_s_barrier();
            asm volatile("s_waitcnt lgkmcnt(0)" ::: "memory");
            __builtin_amdgcn_sched_barrier(0);
            __builtin_amdgcn_s_setprio(1);
#pragma unroll
            for (int s = 0; s < 4; ++s)
#pragma unroll
                for (int m = 0; m < 4; ++m)
                    acc[4 + s][m] = __builtin_amdgcn_mfma_f32_16x16x32_f16(af1[s], bf[m], acc[4 + s][m], 0, 0, 0);
            __builtin_amdgcn_s_setprio(0);
            // counted drain: chunk n+1 must be in LDS; chunk n+2 stays in flight
            if (n == 190) { asm volatile("s_waitcnt vmcnt(0)" ::: "memory"); }
            else          { asm volatile("s_waitcnt vmcnt(4)" ::: "memory"); }
            __builtin_amdgcn_s_barrier();
            __builtin_amdgcn_sched_barrier(0);
            cur = (cur + 1 >= 3) ? 0 : cur + 1;
        }

        // ---- fold tile into running argmin (codes ascending per slot)
#pragma unroll
        for (int m = 0; m < 4; ++m) {
            int cl = vt * 256 + (wc * 4 + m) * 16 + l15;   // half-local code
            float cs = csq_s[cl];
            int code = nh * 2048 + cl;
#pragma unroll
            for (int s = 0; s < 8; ++s)
#pragma unroll
                for (int r = 0; r < 4; ++r) {
                    float dd = (zsq_s[wr * 128 + s * 16 + l4 * 4 + r] + cs)
                               - acc[s][m][r] * 0x1p-23f;
                    int pi = s * 4 + r;
                    if (dd < best[pi]) { best[pi] = dd; bidx[pi] = code; }
                }
        }
    }

    // reduce over the 16 code-columns (l15 dimension) lexicographically
#pragma unroll
    for (int off = 8; off >= 1; off >>= 1) {
#pragma unroll
        for (int i = 0; i < 32; ++i) {
            float ob = __shfl_xor(best[i], off, 64);
            int   oi = __shfl_xor(bidx[i], off, 64);
            if (ob < best[i] || (ob == best[i] && oi < bidx[i])) { best[i] = ob; bidx[i] = oi; }
        }
    }
    if (l15 == 0) {
#pragma unroll
        for (int s = 0; s < 8; ++s)
#pragma unroll
            for (int r = 0; r < 4; ++r) {
                int pl = s * 16 + l4 * 4 + r;             // wave-local pixel
                red_b[w][pl] = best[s * 4 + r];
                red_i[w][pl] = bidx[s * 4 + r];
            }
    }
    __syncthreads();
    // combine the 4 code-quarter waves (same wr) per pixel, store (best,idx)
    if (tid < 256) {
        int wrg = tid >> 7, pl = tid & 127;
        float bb = red_b[wrg * 4][pl]; int bi = red_i[wrg * 4][pl];
#pragma unroll
        for (int c = 1; c < 4; ++c) {
            float ob = red_b[wrg * 4 + c][pl]; int oi = red_i[wrg * 4 + c][pl];
            if (ob < bb || (ob == bb && oi < bi)) { bb = ob; bi = oi; }
        }
        bestw[nh * NPIX + bM * 256 + tid] = bb;
        bidxw[nh * NPIX + bM * 256 + tid] = bi;
    }
}

// ---------------- K2b: combine halves (fallback path only)
__global__ __launch_bounds__(256) void k_argmin2(const float* __restrict__ bestw,
                                                 const int* __restrict__ bidxw,
                                                 float* __restrict__ tok_f) {
    int i = blockIdx.x * 256 + threadIdx.x;   // grid 128
    float b0 = bestw[i], b1 = bestw[NPIX + i];
    int   i0 = bidxw[i], i1 = bidxw[NPIX + i];
    tok_f[i] = (float)((b1 < b0) ? i1 : i0);  // half-0 wins ties (lower idx)
}

// ------------------------- K3: gather (fallback path only)
__global__ __launch_bounds__(256) void k_gather(const float* __restrict__ tok_f,
                                                const float* __restrict__ cb,
                                                const float* __restrict__ postcode,
                                                float* __restrict__ zq_out,
                                                float* __restrict__ recon) {
    int b  = blockIdx.x >> 3;                 // grid 1024
    int e0 = (blockIdx.x & 7) * 32;
    int hw = threadIdx.x;
    int t  = (int)tok_f[b * HW + hw];
    const float* cbr = cb       + t * EMB_;
    const float* pcr = postcode + t * CCH;
    float* zq = zq_out + b * (EMB_ * HW) + hw;
    float* rc = recon  + b * (CCH * HW) + hw;
#pragma unroll
    for (int j = 0; j < 32; ++j) {
        int e = e0 + j;
        zq[e * HW] = cbr[e];
        rc[e * HW] = pcr[e];
    }
}

// ---- K3t: LDS-transposed gather (proven R7-R9/R11)
__global__ __launch_bounds__(256) void k_gather2(const float* __restrict__ bestw,
                                                 const int* __restrict__ bidxw,
                                                 const float* __restrict__ cb,
                                                 const float* __restrict__ postcode,
                                                 float* __restrict__ zq_out,
                                                 float* __restrict__ recon,
                                                 float* __restrict__ tok_f) {
    __shared__ float rows[64][257];           // 64.25 KB
    __shared__ int   toks[64];
    const int b    = blockIdx.x >> 1;
    const int half = blockIdx.x & 1;
    const int tid  = threadIdx.x;
    const int p    = tid & 63, eg = tid >> 6;

    for (int g = 0; g < 2; ++g) {
        int px0 = half * 128 + g * 64;
        if (tid < 64) {
            int i = b * HW + px0 + tid;
            float b0 = bestw[i], b1 = bestw[NPIX + i];
            int   i0 = bidxw[i], i1 = bidxw[NPIX + i];
            int t = (b1 < b0) ? i1 : i0;      // identical to k_argmin2
            toks[tid] = t;
            tok_f[i] = (float)t;
        }
        __syncthreads();
        // ---- codebook pass ----
#pragma unroll 8
        for (int r = 0; r < 64; ++r)
            rows[r][tid] = cb[(size_t)toks[r] * EMB_ + tid];   // coalesced 1KB
        __syncthreads();
        {
            float* zq = zq_out + (size_t)b * (EMB_ * HW) + px0 + p;
#pragma unroll 8
            for (int eo = 0; eo < 64; ++eo) {
                int e = eg * 64 + eo;
                zq[(size_t)e * HW] = rows[p][e];               // 256B contiguous
            }
        }
        __syncthreads();
        // ---- postcode pass (reuse rows) ----
#pragma unroll 8
        for (int r = 0; r < 64; ++r)
            rows[r][tid] = postcode[(size_t)toks[r] * CCH + tid];
        __syncthreads();
        {
            float* rc = recon + (size_t)b * (CCH * HW) + px0 + p;
#pragma unroll 8
            for (int eo = 0; eo < 64; ++eo) {
                int e = eg * 64 + eo;
                rc[(size_t)e * HW] = rows[p][e];
            }
        }
        __syncthreads();                       // before next group reuses LDS
    }
}

extern "C" void kernel_launch(void* const* d_in, const int* in_sizes, int n_in,
                              void* d_out, int out_size, void* d_ws, size_t ws_size,
                              hipStream_t stream) {
    const float* x      = (const float*)d_in[0];
    const float* cb     = (const float*)d_in[1];
    const float* pre_w  = (const float*)d_in[2];
    const float* pre_b  = (const float*)d_in[3];
    const float* post_w = (const float*)d_in[4];
    const float* post_b = (const float*)d_in[5];

    float* out    = (float*)d_out;
    float* z_out  = out;                       //  8388608 elems
    float* zq_out = out + 8388608;             //  8388608
    float* recon  = out + 16777216;            //  8388608
    float* tok_f  = out + 25165824;            //    32768

    _Float16* A3 = (_Float16*)zq_out;          // [2048][64][16][8] fp16
    _Float16* B3 = (_Float16*)recon;           // [256][64][16][8]  fp16
    _Float16* W3 = (_Float16*)(recon + 1048576 + 4 * NPIX);  // 131072 f16

    float* csq      = (float*)d_ws;            // 4096 floats
    float* postcode = csq + VOC;               // 4096*256 floats (4 MB)

    size_t need = (size_t)(VOC + VOC * CCH + 4 * NPIX) * sizeof(float);
    bool fused = (ws_size >= need);
    float* bestw; int* bidxw;
    if (fused) {
        bestw = postcode + (size_t)VOC * CCH;  // 2*NPIX floats
        bidxw = (int*)(bestw + 2 * NPIX);      // 2*NPIX ints
    } else {
        bestw = recon + 1048576;
        bidxw = (int*)(recon + 1048576 + 2 * NPIX);
    }

    k_prep <<< 544, 256, 0, stream>>>(cb, post_w, post_b, pre_w,
                                      postcode, B3, csq, W3);
    k_zgemm<<< 512, 512, 0, stream>>>(x, W3, pre_b, z_out, A3);
    k_dist <<< 256, 512, 0, stream>>>(z_out, A3, B3, csq, bestw, bidxw);
    if (fused) {
        k_gather2<<< 256, 256, 0, stream>>>(bestw, bidxw, cb, postcode,
                                            zq_out, recon, tok_f);
    } else {
        k_argmin2<<< 128, 256, 0, stream>>>(bestw, bidxw, tok_f);
        k_gather <<<1024, 256, 0, stream>>>(tok_f, cb, postcode, zq_out, recon);
    }
}

// Round 13
// 390.002 us; speedup vs baseline: 1.0305x; 1.0305x over previous
//
#include <hip/hip_runtime.h>
#include <float.h>
#include <stdint.h>

// Problem constants
#define BB   128      // bs*t
#define CCH  256      // z channels
#define EMB_ 256      // embedding dim
#define HW   256      // h*w
#define NPIX 32768    // BB*HW
#define VOC  4096

typedef _Float16 f16x8 __attribute__((ext_vector_type(8)));
typedef float    f32x4 __attribute__((ext_vector_type(4)));

// async global->LDS, 16B per lane, dest = wave-uniform base + lane*16
__device__ __forceinline__ void async16(void* lds, const void* g) {
    __builtin_amdgcn_global_load_lds((const __attribute__((address_space(1))) uint32_t*)g,
                                     (__attribute__((address_space(3))) uint32_t*)lds,
                                     16, 0, 0);
}

// ===================== K_PREP: small preprocessing (544 blocks) ============
__global__ __launch_bounds__(256) void k_prep(const float* __restrict__ cb,
                                              const float* __restrict__ post_w,
                                              const float* __restrict__ post_b,
                                              const float* __restrict__ pre_w,
                                              float* __restrict__ postcode,
                                              _Float16* __restrict__ B3,
                                              float* __restrict__ csq,
                                              _Float16* __restrict__ W3) {
    __shared__ float smem[4352];              // 17 KB union
    const int bid = blockIdx.x;
    const int tid = threadIdx.x;

    if (bid < 256) {
        // ---------------- postcode ----------------
        float (*cbs)[EMB_] = (float(*)[EMB_])smem;          // [16][256]
        int v0 = bid * 16;
        int c  = tid;
#pragma unroll
        for (int r = 0; r < 16; ++r)
            cbs[r][c] = cb[(v0 + r) * EMB_ + c];
        __syncthreads();
        float acc[16];
        float bias = post_b[c];
#pragma unroll
        for (int r = 0; r < 16; ++r) acc[r] = bias;
        const float4* w4p = (const float4*)(post_w + c * EMB_);
        for (int e4 = 0; e4 < 64; ++e4) {
            float4 w4 = w4p[e4];
#pragma unroll
            for (int r = 0; r < 16; ++r) {
                float4 c4 = *(const float4*)&cbs[r][e4 * 4];
                acc[r] = fmaf(w4.x, c4.x, fmaf(w4.y, c4.y,
                         fmaf(w4.z, c4.z, fmaf(w4.w, c4.w, acc[r]))));
            }
        }
#pragma unroll
        for (int r = 0; r < 16; ++r)
            postcode[(v0 + r) * CCH + c] = acc[r];
    } else if (bid < 512) {
        // ---------------- prep_c ----------------
        float (*cs)[17] = (float(*)[17])smem;               // [256][17]
        int vg = bid - 256;
        int vr = tid >> 4, e0 = (tid & 15) << 4;
        const float* cp = cb + (vg * 16 + vr) * EMB_ + e0;
#pragma unroll
        for (int j = 0; j < 16; ++j)
            cs[e0 + j][vr] = cp[j];
        __syncthreads();
#pragma unroll
        for (int it = 0; it < 4; ++it) {
            int c = it * 256 + tid;
            int kc8 = c >> 4, row = c & 15;
            int lo = kc8 >> 5;
            int kh = kc8 & 31;
            f16x8 outv;
#pragma unroll
            for (int j = 0; j < 8; ++j) {
                float v = cs[kh * 8 + j][row] * 65536.0f;   // exact 2^16 scale
                _Float16 h = (_Float16)v;
                if (lo) h = (_Float16)(v - (float)h);
                outv[j] = h;
            }
            *(f16x8*)(B3 + ((vg * 64 + kc8) * 128 + row * 8)) = outv;
        }
    } else if (bid < 528) {
        // ---------------- csq ----------------
        int v = (bid - 512) * 256 + tid;
        const float4* row = (const float4*)(cb + v * EMB_);
        float s = 0.f;
#pragma unroll 8
        for (int q = 0; q < 64; ++q) {
            float4 a = row[q];
            s = fmaf(a.x, a.x, fmaf(a.y, a.y, fmaf(a.z, a.z, fmaf(a.w, a.w, s))));
        }
        csq[v] = s;
    } else {
        // ---------------- prep_w: scaled split of pre_w ----------------
        int eg = bid - 528;                   // 0..15
#pragma unroll
        for (int i = 0; i < 4; ++i) {
            int flat = i * 256 + tid;         // 0..1023 = [u64][row16]
            int u = flat >> 4, row = flat & 15;
            int part = u >> 5, c8 = u & 31;
            const float* wp = pre_w + (eg * 16 + row) * CCH + c8 * 8;
            f16x8 outv;
#pragma unroll
            for (int j = 0; j < 8; ++j) {
                float v = wp[j] * 16.0f;                    // exact 2^4 scale
                _Float16 h = (_Float16)v;
                if (part) h = (_Float16)((v - (float)h) * 4096.0f); // exact*2^12, RN
                outv[j] = h;
            }
            *(f16x8*)(W3 + ((eg * 64 + u) * 128 + row * 8)) = outv;
        }
    }
}

// ============ K1: z-GEMM on MFMA (proven v1, session-best config) ==========
__global__ __launch_bounds__(512) void k_zgemm(const float* __restrict__ x,
                                               const _Float16* __restrict__ W3,
                                               const float* __restrict__ pre_b,
                                               float* __restrict__ zout,
                                               _Float16* __restrict__ A3) {
    __shared__ __align__(16) char smem[99328];
    float* pbs = (float*)(smem + 98304);

    const int tid = threadIdx.x;
    const int l   = tid & 63;
    const int w   = tid >> 6;
    const int l15 = l & 15, l4 = l >> 4;
    const int wr  = w >> 2, wc = w & 3;
    const int bM  = blockIdx.x;
    const int b   = bM >> 1, hw0 = (bM & 1) * 128;

    const int xng = tid >> 6, xu = (tid >> 4) & 3, xrow = tid & 15;
    const float* xbase = x + (size_t)b * (CCH * HW) + hw0 + xng * 16 + xrow;

#define STAGE_W(CC, BUF) {                                                   \
    _Pragma("unroll")                                                        \
    for (int i = 0; i < 2; ++i) {                                            \
        int flat = i * 512 + tid; int eg = flat >> 6, sub = flat & 63;       \
        async16((_Float16*)(smem + (BUF) * 16384) + flat * 8,                \
                W3 + (eg * 64 + (CC) * 4) * 128 + sub * 8);                  \
        async16((_Float16*)(smem + 32768 + (BUF) * 16384) + flat * 8,        \
                W3 + (eg * 64 + 32 + (CC) * 4) * 128 + sub * 8);             \
    } }

#define STAGE_X(CC, BUF) {                                                   \
    const float* xp_ = xbase + ((CC) * 32 + xu * 8) * HW;                    \
    f16x8 hv, lv;                                                            \
    _Pragma("unroll")                                                        \
    for (int j = 0; j < 8; ++j) {                                            \
        float xv = 2.0f * xp_[j * HW] - 1.0f;        /* exact */             \
        _Float16 h = (_Float16)xv;                                           \
        lv[j] = (_Float16)((xv - (float)h) * 4096.0f); /* exact*2^12, RN */  \
        hv[j] = h;                                                           \
    }                                                                        \
    *(f16x8*)((_Float16*)(smem + 65536 + (BUF) * 8192) + tid * 8) = hv;      \
    *(f16x8*)((_Float16*)(smem + 81920 + (BUF) * 8192) + tid * 8) = lv;      \
    }

    if (tid < 256) pbs[tid] = pre_b[tid];
    STAGE_W(0, 0)
    STAGE_X(0, 0)
    __syncthreads();

    f32x4 accA[4][4], accB[4][4];
    const f32x4 zero4 = {0.f, 0.f, 0.f, 0.f};
#pragma unroll
    for (int m = 0; m < 4; ++m)
#pragma unroll
        for (int s = 0; s < 4; ++s) { accA[m][s] = zero4; accB[m][s] = zero4; }

    int buf = 0;
    for (int cc = 0; cc < 8; ++cc) {
        if (cc < 7) { STAGE_W(cc + 1, buf ^ 1) STAGE_X(cc + 1, buf ^ 1) }
        const _Float16* WhC = (const _Float16*)(smem + buf * 16384);
        const _Float16* WlC = (const _Float16*)(smem + 32768 + buf * 16384);
        const _Float16* XhC = (const _Float16*)(smem + 65536 + buf * 8192);
        const _Float16* XlC = (const _Float16*)(smem + 81920 + buf * 8192);
        f16x8 whf[4], wlf[4], xhf[4], xlf[4];
#pragma unroll
        for (int m = 0; m < 4; ++m) {
            whf[m] = *(const f16x8*)&WhC[((wc * 4 + m) * 64 + l4 * 16 + l15) * 8];
            wlf[m] = *(const f16x8*)&WlC[((wc * 4 + m) * 64 + l4 * 16 + l15) * 8];
        }
#pragma unroll
        for (int s = 0; s < 4; ++s) {
            xhf[s] = *(const f16x8*)&XhC[((wr * 4 + s) * 64 + l4 * 16 + l15) * 8];
            xlf[s] = *(const f16x8*)&XlC[((wr * 4 + s) * 64 + l4 * 16 + l15) * 8];
        }
#pragma unroll
        for (int m = 0; m < 4; ++m)
#pragma unroll
            for (int s = 0; s < 4; ++s)
                accA[m][s] = __builtin_amdgcn_mfma_f32_16x16x32_f16(whf[m], xhf[s], accA[m][s], 0, 0, 0);
#pragma unroll
        for (int m = 0; m < 4; ++m)
#pragma unroll
            for (int s = 0; s < 4; ++s)
                accB[m][s] = __builtin_amdgcn_mfma_f32_16x16x32_f16(whf[m], xlf[s], accB[m][s], 0, 0, 0);
#pragma unroll
        for (int m = 0; m < 4; ++m)
#pragma unroll
            for (int s = 0; s < 4; ++s)
                accB[m][s] = __builtin_amdgcn_mfma_f32_16x16x32_f16(wlf[m], xhf[s], accB[m][s], 0, 0, 0);
        __syncthreads();
        buf ^= 1;
    }

    // ---- epilogue: z = combine + bias; store z_out; pack A3 (per-wave LDS)
    float* zw = (float*)(smem + w * 5120);    // [64 n][20 floats] this wave
    const size_t zbase = (size_t)b * (EMB_ * HW) + hw0;
#pragma unroll
    for (int m = 0; m < 4; ++m) {
        asm volatile("s_waitcnt lgkmcnt(0)" ::: "memory");   // prev pack reads done
        __builtin_amdgcn_sched_barrier(0);
        f32x4 zv[4];
#pragma unroll
        for (int s = 0; s < 4; ++s) {
#pragma unroll
            for (int r = 0; r < 4; ++r) {
                float g = fmaf(accB[m][s][r], 0x1p-12f, accA[m][s][r]) * 0x1p-4f;
                zv[s][r] = g + pbs[wc * 64 + m * 16 + l4 * 4 + r];
            }
            *(f32x4*)(zw + (s * 16 + l15) * 20 + l4 * 4) = zv[s];
#pragma unroll
            for (int r = 0; r < 4; ++r)
                zout[zbase + (size_t)(wc * 64 + m * 16 + l4 * 4 + r) * HW
                     + wr * 64 + s * 16 + l15] = zv[s][r];
        }
        asm volatile("s_waitcnt lgkmcnt(0)" ::: "memory");   // zw writes visible
        __builtin_amdgcn_sched_barrier(0);
#pragma unroll
        for (int o = 0; o < 4; ++o) {
            int flat = o * 64 + l;
            int part = flat >> 7, rest = flat & 127;
            int pg = rest >> 5, uq = (rest >> 4) & 1, row = rest & 15;
            int nloc = pg * 16 + row;
            float4 va = *(const float4*)(zw + nloc * 20 + uq * 8);
            float4 vb = *(const float4*)(zw + nloc * 20 + uq * 8 + 4);
            float vs[8] = {va.x, va.y, va.z, va.w, vb.x, vb.y, vb.z, vb.w};
            f16x8 outv;
#pragma unroll
            for (int j = 0; j < 8; ++j) {
                float v = vs[j] * 256.0f;                    // exact 2^8 scale
                _Float16 h = (_Float16)v;
                if (part) h = (_Float16)(v - (float)h);      // exact residual, RN
                outv[j] = h;
            }
            *(f16x8*)(A3 + ((size_t)(bM * 8 + wr * 4 + pg) * 64
                            + part * 32 + wc * 8 + m * 2 + uq) * 128 + row * 8) = outv;
        }
    }
#undef STAGE_W
#undef STAGE_X
}

// --------- K2 staging: BK=32 chunk = 4 contiguous kc8 units at offset kA/kB.
__device__ __forceinline__ void issueA(const _Float16* __restrict__ A3, int bM,
                                       int w, int l, _Float16* dst, int kA) {
#pragma unroll
    for (int i = 0; i < 2; ++i) {
        int pg = 2 * w + i;                           // pixel-group 0..15
        const _Float16* g = A3 + ((bM * 16 + pg) * 64 + kA) * 128 + l * 8;
        async16(dst + pg * 512, g);                   // linear both sides
    }
}

__device__ __forceinline__ void issueB(const _Float16* __restrict__ B3, int vgbase,
                                       int w, int l, _Float16* dst, int kB) {
#pragma unroll
    for (int i = 0; i < 2; ++i) {
        int vg = 2 * w + i;                           // code-group 0..15
        const _Float16* g = B3 + ((vgbase + vg) * 64 + kB) * 128 + l * 8;
        async16(dst + vg * 512, g);
    }
}

// --------------------------------- K2: MFMA distance GEMM + fused argmin
// R4/R5 proven config (234-240 us, no spill): 3 buffers, runtime cur,
// depth-2 prefetch, vmcnt(4), 2 phases per BK=32 chunk.
__global__ __launch_bounds__(512) void k_dist(const float* __restrict__ zout,
                                              const _Float16* __restrict__ A3,
                                              const _Float16* __restrict__ B3,
                                              const float* __restrict__ csq,
                                              float* __restrict__ bestw,
                                              int* __restrict__ bidxw) {
    __shared__ __align__(16) _Float16 Ab[3][8192];    // 48 KB (16 KB/chunk)
    __shared__ __align__(16) _Float16 Bb[3][8192];    // 48 KB
    __shared__ float csq_s[2048];                     // 8 KB (this half only)
    __shared__ float zsq_s[256];
    __shared__ float red_b[8][128];
    __shared__ int   red_i[8][128];

    const int tid = threadIdx.x;
    const int l   = tid & 63;
    const int w   = tid >> 6;
    const int l15 = l & 15, l4 = l >> 4;
    const int wr  = w >> 2, wc = w & 3;               // 2M x 4N wave grid
    const int bM  = blockIdx.x & 127;                 // M-tile (256 pixels)
    const int nh  = blockIdx.x >> 7;                  // code half 0/1
    const int vgb = nh * 128;                         // B3 group base

    // prologue: stage chunks 0 and 1
    issueA(A3, bM, w, l, Ab[0], 0);
    issueB(B3, vgb, w, l, Bb[0], 0);
    issueA(A3, bM, w, l, Ab[1], 4);
    issueB(B3, vgb, w, l, Bb[1], 4);

    // csq half -> LDS
#pragma unroll
    for (int j = 0; j < 4; ++j) csq_s[j * 512 + tid] = csq[nh * 2048 + j * 512 + tid];

    // zsq: serial fmaf chain over e (identical rounding to passing kernel)
    if (tid < 256) {
        const float* zp = zout + bM * (EMB_ * HW) + tid;
        float s = 0.f;
        for (int k = 0; k < 256; ++k) { float zv = zp[k * HW]; s = fmaf(zv, zv, s); }
        zsq_s[tid] = s;
    }
    __syncthreads();   // one-time full drain: chunks 0,1 + csq_s + zsq_s ready

    float best[32]; int bidx[32];
#pragma unroll
    for (int i = 0; i < 32; ++i) { best[i] = FLT_MAX; bidx[i] = 0; }

    const f32x4 zero4 = {0.f, 0.f, 0.f, 0.f};
    int cur = 0;
    for (int vt = 0; vt < 8; ++vt) {
        f32x4 acc[8][4];
#pragma unroll
        for (int s = 0; s < 8; ++s)
#pragma unroll
            for (int m = 0; m < 4; ++m) acc[s][m] = zero4;

        for (int kc = 0; kc < 24; ++kc) {
            const int n = vt * 24 + kc;               // global chunk 0..191
            int kc2 = kc + 2, vt2 = vt;
            if (kc2 >= 24) { kc2 -= 24; ++vt2; }
            const int nxt = (cur + 2 >= 3) ? cur - 1 : cur + 2;
            const bool pf = (vt2 < 8);
            const int kA2 = ((kc2 >= 16) ? 32 : 0) + (kc2 & 7) * 4;
            const int kB2 = ((kc2 >= 8 && kc2 < 16) ? 32 : 0) + (kc2 & 7) * 4;

            // ---------------- phase 0: s-half 0 ----------------
            f16x8 af0[4], bf[4];
#pragma unroll
            for (int s = 0; s < 4; ++s)
                af0[s] = *(const f16x8*)&Ab[cur][(wr * 8 + s) * 512 + l4 * 128 + l15 * 8];
#pragma unroll
            for (int m = 0; m < 4; ++m)
                bf[m] = *(const f16x8*)&Bb[cur][(wc * 4 + m) * 512 + l4 * 128 + l15 * 8];
            if (pf) issueA(A3, bM, w, l, Ab[nxt], kA2);
            __builtin_amdgcn_s_barrier();
            asm volatile("s_waitcnt lgkmcnt(0)" ::: "memory");
            __builtin_amdgcn_sched_barrier(0);
            __builtin_amdgcn_s_setprio(1);
#pragma unroll
            for (int s = 0; s < 4; ++s)
#pragma unroll
                for (int m = 0; m < 4; ++m)
                    acc[s][m] = __builtin_amdgcn_mfma_f32_16x16x32_f16(af0[s], bf[m], acc[s][m], 0, 0, 0);
            __builtin_amdgcn_s_setprio(0);
            __builtin_amdgcn_s_barrier();

            // ---------------- phase 1: s-half 1 ----------------
            f16x8 af1[4];
#pragma unroll
            for (int s = 0; s < 4; ++s)
                af1[s] = *(const f16x8*)&Ab[cur][(wr * 8 + 4 + s) * 512 + l4 * 128 + l15 * 8];
            if (pf) issueB(B3, vgb + vt2 * 16, w, l, Bb[nxt], kB2);
            __builtin_amdgcn_s_barrier();
            asm volatile("s_waitcnt lgkmcnt(0)" ::: "memory");
            __builtin_amdgcn_sched_barrier(0);
            __builtin_amdgcn_s_setprio(1);
#pragma unroll
            for (int s = 0; s < 4; ++s)
#pragma unroll
                for (int m = 0; m < 4; ++m)
                    acc[4 + s][m] = __builtin_amdgcn_mfma_f32_16x16x32_f16(af1[s], bf[m], acc[4 + s][m], 0, 0, 0);
            __builtin_amdgcn_s_setprio(0);
            // counted drain: chunk n+1 must be in LDS; chunk n+2 stays in flight
            if (n == 190) { asm volatile("s_waitcnt vmcnt(0)" ::: "memory"); }
            else          { asm volatile("s_waitcnt vmcnt(4)" ::: "memory"); }
            __builtin_amdgcn_s_barrier();
            __builtin_amdgcn_sched_barrier(0);
            cur = (cur + 1 >= 3) ? 0 : cur + 1;
        }

        // ---- fold tile into running argmin (codes ascending per slot)
#pragma unroll
        for (int m = 0; m < 4; ++m) {
            int cl = vt * 256 + (wc * 4 + m) * 16 + l15;   // half-local code
            float cs = csq_s[cl];
            int code = nh * 2048 + cl;
#pragma unroll
            for (int s = 0; s < 8; ++s)
#pragma unroll
                for (int r = 0; r < 4; ++r) {
                    float dd = (zsq_s[wr * 128 + s * 16 + l4 * 4 + r] + cs)
                               - acc[s][m][r] * 0x1p-23f;
                    int pi = s * 4 + r;
                    if (dd < best[pi]) { best[pi] = dd; bidx[pi] = code; }
                }
        }
    }

    // reduce over the 16 code-columns (l15 dimension) lexicographically
#pragma unroll
    for (int off = 8; off >= 1; off >>= 1) {
#pragma unroll
        for (int i = 0; i < 32; ++i) {
            float ob = __shfl_xor(best[i], off, 64);
            int   oi = __shfl_xor(bidx[i], off, 64);
            if (ob < best[i] || (ob == best[i] && oi < bidx[i])) { best[i] = ob; bidx[i] = oi; }
        }
    }
    if (l15 == 0) {
#pragma unroll
        for (int s = 0; s < 8; ++s)
#pragma unroll
            for (int r = 0; r < 4; ++r) {
                int pl = s * 16 + l4 * 4 + r;             // wave-local pixel
                red_b[w][pl] = best[s * 4 + r];
                red_i[w][pl] = bidx[s * 4 + r];
            }
    }
    __syncthreads();
    // combine the 4 code-quarter waves (same wr) per pixel, store (best,idx)
    if (tid < 256) {
        int wrg = tid >> 7, pl = tid & 127;
        float bb = red_b[wrg * 4][pl]; int bi = red_i[wrg * 4][pl];
#pragma unroll
        for (int c = 1; c < 4; ++c) {
            float ob = red_b[wrg * 4 + c][pl]; int oi = red_i[wrg * 4 + c][pl];
            if (ob < bb || (ob == bb && oi < bi)) { bb = ob; bi = oi; }
        }
        bestw[nh * NPIX + bM * 256 + tid] = bb;
        bidxw[nh * NPIX + bM * 256 + tid] = bi;
    }
}

// ---------------- K2b: combine halves (fallback path only)
__global__ __launch_bounds__(256) void k_argmin2(const float* __restrict__ bestw,
                                                 const int* __restrict__ bidxw,
                                                 float* __restrict__ tok_f) {
    int i = blockIdx.x * 256 + threadIdx.x;   // grid 128
    float b0 = bestw[i], b1 = bestw[NPIX + i];
    int   i0 = bidxw[i], i1 = bidxw[NPIX + i];
    tok_f[i] = (float)((b1 < b0) ? i1 : i0);  // half-0 wins ties (lower idx)
}

// ------------------------- K3: gather (fallback path only)
__global__ __launch_bounds__(256) void k_gather(const float* __restrict__ tok_f,
                                                const float* __restrict__ cb,
                                                const float* __restrict__ postcode,
                                                float* __restrict__ zq_out,
                                                float* __restrict__ recon) {
    int b  = blockIdx.x >> 3;                 // grid 1024
    int e0 = (blockIdx.x & 7) * 32;
    int hw = threadIdx.x;
    int t  = (int)tok_f[b * HW + hw];
    const float* cbr = cb       + t * EMB_;
    const float* pcr = postcode + t * CCH;
    float* zq = zq_out + b * (EMB_ * HW) + hw;
    float* rc = recon  + b * (CCH * HW) + hw;
#pragma unroll
    for (int j = 0; j < 32; ++j) {
        int e = e0 + j;
        zq[e * HW] = cbr[e];
        rc[e * HW] = pcr[e];
    }
}

// ---- K3t: LDS-transposed gather (proven R7-R9/R11)
__global__ __launch_bounds__(256) void k_gather2(const float* __restrict__ bestw,
                                                 const int* __restrict__ bidxw,
                                                 const float* __restrict__ cb,
                                                 const float* __restrict__ postcode,
                                                 float* __restrict__ zq_out,
                                                 float* __restrict__ recon,
                                                 float* __restrict__ tok_f) {
    __shared__ float rows[64][257];           // 64.25 KB
    __shared__ int   toks[64];
    const int b    = blockIdx.x >> 1;
    const int half = blockIdx.x & 1;
    const int tid  = threadIdx.x;
    const int p    = tid & 63, eg = tid >> 6;

    for (int g = 0; g < 2; ++g) {
        int px0 = half * 128 + g * 64;
        if (tid < 64) {
            int i = b * HW + px0 + tid;
            float b0 = bestw[i], b1 = bestw[NPIX + i];
            int   i0 = bidxw[i], i1 = bidxw[NPIX + i];
            int t = (b1 < b0) ? i1 : i0;      // identical to k_argmin2
            toks[tid] = t;
            tok_f[i] = (float)t;
        }
        __syncthreads();
        // ---- codebook pass ----
#pragma unroll 8
        for (int r = 0; r < 64; ++r)
            rows[r][tid] = cb[(size_t)toks[r] * EMB_ + tid];   // coalesced 1KB
        __syncthreads();
        {
            float* zq = zq_out + (size_t)b * (EMB_ * HW) + px0 + p;
#pragma unroll 8
            for (int eo = 0; eo < 64; ++eo) {
                int e = eg * 64 + eo;
                zq[(size_t)e * HW] = rows[p][e];               // 256B contiguous
            }
        }
        __syncthreads();
        // ---- postcode pass (reuse rows) ----
#pragma unroll 8
        for (int r = 0; r < 64; ++r)
            rows[r][tid] = postcode[(size_t)toks[r] * CCH + tid];
        __syncthreads();
        {
            float* rc = recon + (size_t)b * (CCH * HW) + px0 + p;
#pragma unroll 8
            for (int eo = 0; eo < 64; ++eo) {
                int e = eg * 64 + eo;
                rc[(size_t)e * HW] = rows[p][e];
            }
        }
        __syncthreads();                       // before next group reuses LDS
    }
}

extern "C" void kernel_launch(void* const* d_in, const int* in_sizes, int n_in,
                              void* d_out, int out_size, void* d_ws, size_t ws_size,
                              hipStream_t stream) {
    const float* x      = (const float*)d_in[0];
    const float* cb     = (const float*)d_in[1];
    const float* pre_w  = (const float*)d_in[2];
    const float* pre_b  = (const float*)d_in[3];
    const float* post_w = (const float*)d_in[4];
    const float* post_b = (const float*)d_in[5];

    float* out    = (float*)d_out;
    float* z_out  = out;                       //  8388608 elems
    float* zq_out = out + 8388608;             //  8388608
    float* recon  = out + 16777216;            //  8388608
    float* tok_f  = out + 25165824;            //    32768

    _Float16* A3 = (_Float16*)zq_out;          // [2048][64][16][8] fp16
    _Float16* B3 = (_Float16*)recon;           // [256][64][16][8]  fp16
    _Float16* W3 = (_Float16*)(recon + 1048576 + 4 * NPIX);  // 131072 f16

    float* csq      = (float*)d_ws;            // 4096 floats
    float* postcode = csq + VOC;               // 4096*256 floats (4 MB)

    size_t need = (size_t)(VOC + VOC * CCH + 4 * NPIX) * sizeof(float);
    bool fused = (ws_size >= need);
    float* bestw; int* bidxw;
    if (fused) {
        bestw = postcode + (size_t)VOC * CCH;  // 2*NPIX floats
        bidxw = (int*)(bestw + 2 * NPIX);      // 2*NPIX ints
    } else {
        bestw = recon + 1048576;
        bidxw = (int*)(recon + 1048576 + 2 * NPIX);
    }

    k_prep <<< 544, 256, 0, stream>>>(cb, post_w, post_b, pre_w,
                                      postcode, B3, csq, W3);
    k_zgemm<<< 256, 512, 0, stream>>>(x, W3, pre_b, z_out, A3);
    k_dist <<< 256, 512, 0, stream>>>(z_out, A3, B3, csq, bestw, bidxw);
    if (fused) {
        k_gather2<<< 256, 256, 0, stream>>>(bestw, bidxw, cb, postcode,
                                            zq_out, recon, tok_f);
    } else {
        k_argmin2<<< 128, 256, 0, stream>>>(bestw, bidxw, tok_f);
        k_gather <<<1024, 256, 0, stream>>>(tok_f, cb, postcode, zq_out, recon);
    }
}